// Round 1
// baseline (236.862 us; speedup 1.0000x reference)
//
#include <hip/hip_runtime.h>
#include <math.h>

#define TOK_TOTAL 16384
#define D_MODEL   2048
#define NEXP      64
#define TPB       64          // tokens per block
#define KC        32          // K chunk
#define NCHUNK    (D_MODEL / KC)
#define THREADS   256

#define ASTRIDE   33          // padded LDS row stride (doubles) -> conflict-free
#define BUFSZ     (64 * ASTRIDE)   // 2112 doubles per tile
#define LOGSTRIDE 66          // padded logits stride (doubles)

__global__ __launch_bounds__(THREADS, 1)
void router_main(const float* __restrict__ x, const float* __restrict__ W,
                 float* __restrict__ out, float* __restrict__ ws)
{
    // LDS: [A0 | W0 | A1 | W1], each 64x33 doubles. Logits alias A0|W0 after K loop.
    __shared__ double smem[4 * BUFSZ];
    __shared__ int   s_bi[TPB], s_si[TPB];
    __shared__ float s_s0[TPB], s_s1[TPB];
    __shared__ float part[NEXP][17];

    const int t  = threadIdx.x;
    const int tm = t >> 4;      // token group 0..15 (4 tokens each)
    const int te = t & 15;      // expert group 0..15 (4 experts each)
    const long tok0 = (long)blockIdx.x * TPB;

    double acc[4][4];
    #pragma unroll
    for (int i = 0; i < 4; ++i)
        #pragma unroll
        for (int j = 0; j < 4; ++j) acc[i][j] = 0.0;

    // ---- prologue: stage chunk 0 into buffer 0 ----
    #pragma unroll
    for (int jj = 0; jj < 2; ++jj) {
        int f   = t + THREADS * jj;
        int row = f >> 3;
        int c4  = (f & 7) * 4;
        float4 xv = *(const float4*)(x + (tok0 + row) * D_MODEL + c4);
        float4 wv = *(const float4*)(W + (long)row * D_MODEL + c4);
        double* ap = smem + row * ASTRIDE + c4;
        ap[0] = (double)xv.x; ap[1] = (double)xv.y; ap[2] = (double)xv.z; ap[3] = (double)xv.w;
        double* wp = smem + BUFSZ + row * ASTRIDE + c4;
        wp[0] = (double)wv.x; wp[1] = (double)wv.y; wp[2] = (double)wv.z; wp[3] = (double)wv.w;
    }
    __syncthreads();

    // ---- main K loop, double-buffered ----
    for (int kc = 0; kc < NCHUNK; ++kc) {
        const int cur = kc & 1;
        float4 xr[2], wr[2];
        const bool pre = (kc + 1 < NCHUNK);
        if (pre) {
            const int k0n = (kc + 1) * KC;
            #pragma unroll
            for (int jj = 0; jj < 2; ++jj) {
                int f   = t + THREADS * jj;
                int row = f >> 3;
                int c4  = (f & 7) * 4;
                xr[jj] = *(const float4*)(x + (tok0 + row) * D_MODEL + k0n + c4);
                wr[jj] = *(const float4*)(W + (long)row * D_MODEL + k0n + c4);
            }
        }
        const double* Ab = smem + cur * 2 * BUFSZ + (4 * tm) * ASTRIDE;
        const double* Bb = smem + cur * 2 * BUFSZ + BUFSZ + (4 * te) * ASTRIDE;
        #pragma unroll 4
        for (int kk = 0; kk < KC; ++kk) {
            double a0 = Ab[0 * ASTRIDE + kk];
            double a1 = Ab[1 * ASTRIDE + kk];
            double a2 = Ab[2 * ASTRIDE + kk];
            double a3 = Ab[3 * ASTRIDE + kk];
            double b0 = Bb[0 * ASTRIDE + kk];
            double b1 = Bb[1 * ASTRIDE + kk];
            double b2 = Bb[2 * ASTRIDE + kk];
            double b3 = Bb[3 * ASTRIDE + kk];
            acc[0][0] = fma(a0, b0, acc[0][0]);
            acc[0][1] = fma(a0, b1, acc[0][1]);
            acc[0][2] = fma(a0, b2, acc[0][2]);
            acc[0][3] = fma(a0, b3, acc[0][3]);
            acc[1][0] = fma(a1, b0, acc[1][0]);
            acc[1][1] = fma(a1, b1, acc[1][1]);
            acc[1][2] = fma(a1, b2, acc[1][2]);
            acc[1][3] = fma(a1, b3, acc[1][3]);
            acc[2][0] = fma(a2, b0, acc[2][0]);
            acc[2][1] = fma(a2, b1, acc[2][1]);
            acc[2][2] = fma(a2, b2, acc[2][2]);
            acc[2][3] = fma(a2, b3, acc[2][3]);
            acc[3][0] = fma(a3, b0, acc[3][0]);
            acc[3][1] = fma(a3, b1, acc[3][1]);
            acc[3][2] = fma(a3, b2, acc[3][2]);
            acc[3][3] = fma(a3, b3, acc[3][3]);
        }
        if (pre) {
            double* Ad = smem + (cur ^ 1) * 2 * BUFSZ;
            double* Wd = Ad + BUFSZ;
            #pragma unroll
            for (int jj = 0; jj < 2; ++jj) {
                int f   = t + THREADS * jj;
                int row = f >> 3;
                int c4  = (f & 7) * 4;
                double* ap = Ad + row * ASTRIDE + c4;
                ap[0] = (double)xr[jj].x; ap[1] = (double)xr[jj].y;
                ap[2] = (double)xr[jj].z; ap[3] = (double)xr[jj].w;
                double* wp = Wd + row * ASTRIDE + c4;
                wp[0] = (double)wr[jj].x; wp[1] = (double)wr[jj].y;
                wp[2] = (double)wr[jj].z; wp[3] = (double)wr[jj].w;
            }
        }
        __syncthreads();
    }

    // ---- dump logits to LDS (aliases buffer 0 region; safe after final sync) ----
    double* logits = smem;
    #pragma unroll
    for (int i = 0; i < 4; ++i)
        #pragma unroll
        for (int j = 0; j < 4; ++j)
            logits[(4 * tm + i) * LOGSTRIDE + (4 * te + j)] = acc[i][j];
    __syncthreads();

    // ---- top-2 per token (fp64 compare; ties -> lower index, matches lax.top_k) ----
    if (t < TPB) {
        const double* lrow = logits + t * LOGSTRIDE;
        double best = -1e300, sec = -1e300;
        int bi = 0, si = 0;
        for (int e = 0; e < NEXP; ++e) {
            double v = lrow[e];
            if (v > best)      { sec = best; si = bi; best = v; bi = e; }
            else if (v > sec)  { sec = v;  si = e; }
        }
        // normalized top-2 scores: softmax denominator cancels
        double ex  = exp(sec - best);
        double inv = 1.0 / (1.0 + ex);
        s_bi[t] = bi; s_si[t] = si;
        s_s0[t] = (float)inv;
        s_s1[t] = (float)(ex * inv);
        float* outI = out + (long)TOK_TOTAL * NEXP;
        long tok = tok0 + t;
        outI[2 * tok + 0] = (float)bi;
        outI[2 * tok + 1] = (float)si;
    }
    __syncthreads();

    // ---- gates (dense scatter) + per-block expert counts ----
    const int ebase = te * 4;
    float c0 = 0.f, c1 = 0.f, c2 = 0.f, c3 = 0.f;
    #pragma unroll
    for (int q = 0; q < 4; ++q) {
        int row = tm + q * 16;
        int gi0 = s_bi[row], gi1 = s_si[row];
        float g0 = s_s0[row], g1 = s_s1[row];
        float v0 = (ebase + 0 == gi0) ? g0 : ((ebase + 0 == gi1) ? g1 : 0.f);
        float v1 = (ebase + 1 == gi0) ? g0 : ((ebase + 1 == gi1) ? g1 : 0.f);
        float v2 = (ebase + 2 == gi0) ? g0 : ((ebase + 2 == gi1) ? g1 : 0.f);
        float v3 = (ebase + 3 == gi0) ? g0 : ((ebase + 3 == gi1) ? g1 : 0.f);
        c0 += v0; c1 += v1; c2 += v2; c3 += v3;
        float4 v = make_float4(v0, v1, v2, v3);
        *(float4*)(out + (tok0 + row) * NEXP + ebase) = v;
    }
    part[ebase + 0][tm] = c0;
    part[ebase + 1][tm] = c1;
    part[ebase + 2][tm] = c2;
    part[ebase + 3][tm] = c3;
    __syncthreads();
    if (t < NEXP) {
        float s = 0.f;
        #pragma unroll
        for (int m = 0; m < 16; ++m) s += part[t][m];
        ws[blockIdx.x * NEXP + t] = s;
    }
}

__global__ void router_loss(const float* __restrict__ ws, float* __restrict__ out)
{
    __shared__ double sc[NEXP];
    const int e = threadIdx.x;   // 64 threads
    double csum = 0.0;
    for (int b = 0; b < TOK_TOTAL / TPB; ++b) csum += (double)ws[b * NEXP + e];
    sc[e] = csum;
    __syncthreads();
    if (e == 0) {
        double tot = 0.0;
        for (int i = 0; i < NEXP; ++i) tot += sc[i];
        double loss = 0.0;
        for (int i = 0; i < NEXP; ++i) {
            double d = sc[i] / tot * (double)NEXP - 1.0;
            loss += d * d;
        }
        out[(long)TOK_TOTAL * NEXP + (long)TOK_TOTAL * 2] = (float)(loss / NEXP);
    }
}

extern "C" void kernel_launch(void* const* d_in, const int* in_sizes, int n_in,
                              void* d_out, int out_size, void* d_ws, size_t ws_size,
                              hipStream_t stream)
{
    const float* x = (const float*)d_in[0];
    const float* W = (const float*)d_in[1];
    // d_in[2] = n_active (==2), d_in[3] = capacity — fixed for this problem size.
    float* out = (float*)d_out;
    float* ws  = (float*)d_ws;   // needs 256*64 floats = 64 KB

    router_main<<<TOK_TOTAL / TPB, THREADS, 0, stream>>>(x, W, out, ws);
    router_loss<<<1, NEXP, 0, stream>>>(ws, out);
}